// Round 1
// baseline (86.274 us; speedup 1.0000x reference)
//
#include <hip/hip_runtime.h>
#include <hip/hip_bf16.h>

// Problem constants (fixed by setup_inputs):
//   T=36, Q=2048, C=42 (num_classes=41), N=128
// Inputs (d_in order):
//   0: pred_logits  float32 [T*Q, C]
//   1: pred_boxes   float32 [T*Q, 4]   (cx,cy,w,h)
//   2: tgt_labels   int32   [N*T]
//   3: tgt_boxes    float32 [N*T, 4]
//   4: tgt_valid    int32   [N*T]
//   5: tgt_original_valid int32 [N*T]
// Output: float32 [Q, N] row-major, out[q*N+n]
//
// R7 = R6 softmax kernel unchanged; cost_kernel rewritten for VALU-op
// reduction (the kernel is VALU-throughput-bound, ~20x above the HBM
// roofline):
//   - IEEE f32 divide (v_div_scale/.../v_div_fixup, ~10 slots) replaced by
//     v_rcp_f32 + mul (<=1 ulp, vs 8.9e-3 absmax budget).
//   - n-inner loop NB=8: pred-box load + cxcywh->xyxy (8 fma) + area_p
//     amortized over 8 n instead of recomputed per (n,t).
//   - tgt xyxy precomputed once in LDS staging; gather byte offset
//     (id*Q*2) precomputed and packed with the valid bit.
//   - l1 0.25-scale and (l1 - p - iou) folded into fma chain.

constexpr int T = 36;
constexpr int Q = 2048;
constexpr int C = 42;
constexpr int N = 128;

// ---------------------------------------------------------------------------
// Kernel 1: row softmax of logits, written TRANSPOSED as P2[t][c][q] (bf16).
// (unchanged from R6 — measured good; ~5 us of the total)
// ---------------------------------------------------------------------------
__global__ __launch_bounds__(256) void softmax_transpose_kernel(
    const float* __restrict__ logits, __hip_bfloat16* __restrict__ P2) {
  constexpr int QB = 64;
  constexpr int LS = C + 1;  // 43: gcd(43,32)=1 -> conflict-free

  __shared__ float tile[QB * LS];
  __shared__ float s_max[4 * QB];
  __shared__ float s_sum[4 * QB];
  __shared__ float s_rinv[QB];

  const int t = blockIdx.y;
  const int q0 = blockIdx.x * QB;
  const int tid = threadIdx.x;

  const float* src = logits + ((size_t)t * Q + q0) * C;
  for (int i = tid; i < QB * C; i += 256) {
    int r = i / C, c = i % C;
    tile[r * LS + c] = src[i];
  }
  __syncthreads();

  const int part = tid >> 6;
  const int row = tid & 63;
  const int c0 = (part < 2) ? part * 11 : 22 + (part - 2) * 10;
  const int c1 = (part < 2) ? c0 + 11 : c0 + 10;

  float m = -1e30f;
  for (int c = c0; c < c1; ++c) m = fmaxf(m, tile[row * LS + c]);
  s_max[part * QB + row] = m;
  __syncthreads();

  m = fmaxf(fmaxf(s_max[row], s_max[QB + row]),
            fmaxf(s_max[2 * QB + row], s_max[3 * QB + row]));
  float s = 0.f;
  for (int c = c0; c < c1; ++c) {
    float e = __expf(tile[row * LS + c] - m);
    tile[row * LS + c] = e;
    s += e;
  }
  s_sum[part * QB + row] = s;
  __syncthreads();

  if (part == 0) {
    float stot = s_sum[row] + s_sum[QB + row] + s_sum[2 * QB + row] +
                 s_sum[3 * QB + row];
    s_rinv[row] = 1.f / stot;
  }
  __syncthreads();

  for (int i = tid; i < QB * C / 2; i += 256) {
    int c = i >> 5;
    int r2 = i & 31;
    float v0 = tile[(2 * r2) * LS + c] * s_rinv[2 * r2];
    float v1 = tile[(2 * r2 + 1) * LS + c] * s_rinv[2 * r2 + 1];
    __hip_bfloat162 pk;
    pk.x = __float2bfloat16(v0);
    pk.y = __float2bfloat16(v1);
    *(__hip_bfloat162*)(P2 + (size_t)(t * C + c) * Q + q0 + 2 * r2) = pk;
  }
}

// ---------------------------------------------------------------------------
// Kernel 2: cost[q,n] = sum_t valid*(l1 - prob - iou) / denom[n].
// Block = 512 threads = 64 q-lanes x 8 waves; waves split t (4 or 5 each);
// inner loop unrolled over NB=8 n's. Grid (32,16) = 512 blocks x 8 waves
// = 16 waves/CU. Valid-check remains wave-uniform (n,t uniform per step).
// Gather: 64 lanes -> 64 consecutive bf16 = one 128B line.
// ---------------------------------------------------------------------------
constexpr int NB = 8;

__global__ __launch_bounds__(512) void cost_kernel(
    const __hip_bfloat16* __restrict__ P2, const float* __restrict__ pred_boxes,
    const int* __restrict__ labels, const float* __restrict__ tboxes,
    const int* __restrict__ valid, const int* __restrict__ ovalid,
    float* __restrict__ out) {
  constexpr int RS = NB + 1;  // 9: gcd(9,32)=1 -> conflict-free reduction LDS

  const int q0 = blockIdx.x * 64;
  const int n0 = blockIdx.y * NB;
  const int tid = threadIdx.x;  // 0..511
  const int lane = tid & 63;    // q offset
  const int wave = tid >> 6;    // 0..7, splits t
  const int q = q0 + lane;

  __shared__ float4 s_tbA[NB * T];   // tgt cxcywh
  __shared__ float4 s_tbB[NB * T];   // tgt xyxy (precomputed)
  __shared__ int s_pk[NB * T];       // (valid<<24) | byte offset id*Q*2
  __shared__ float s_rden[NB];       // 1/denom
  __shared__ float s_red[8 * 64 * RS];

  for (int i = tid; i < NB * T; i += 512) {
    int n = n0 + i / T;
    int t = i % T;
    int g = n * T + t;
    int id = (ovalid[g] == 0) ? (C - 1) : labels[g];
    s_pk[i] = (valid[g] << 24) | (id * (Q * 2));  // bf16 byte offset
    float4 tb = ((const float4*)tboxes)[g];
    s_tbA[i] = tb;
    float4 B;
    B.x = fmaf(-0.5f, tb.z, tb.x);
    B.y = fmaf(-0.5f, tb.w, tb.y);
    B.z = fmaf(0.5f, tb.z, tb.x);
    B.w = fmaf(0.5f, tb.w, tb.y);
    s_tbB[i] = B;
  }
  if (tid < NB) {
    int n = n0 + tid;
    int s = 0;
    for (int t = 0; t < T; ++t) s += valid[n * T + t];
    s_rden[tid] = 1.f / (float)s;
  }
  __syncthreads();

  float acc[NB];
#pragma unroll
  for (int j = 0; j < NB; ++j) acc[j] = 0.f;

  // Wave w handles t in [w*T/8, (w+1)*T/8): counts 4,5,4,5,4,5,4,5.
  const int t_begin = (wave * T) / 8;
  const int t_end = ((wave + 1) * T) / 8;

  for (int t = t_begin; t < t_end; ++t) {
    float4 pb = ((const float4*)pred_boxes)[t * Q + q];
    float px1 = fmaf(-0.5f, pb.z, pb.x);
    float py1 = fmaf(-0.5f, pb.w, pb.y);
    float px2 = fmaf(0.5f, pb.z, pb.x);
    float py2 = fmaf(0.5f, pb.w, pb.y);
    float area_p = pb.z * pb.w;
    const char* pcol = (const char*)(P2 + (size_t)t * C * Q + q);

#pragma unroll
    for (int j = 0; j < NB; ++j) {
      int pk = s_pk[j * T + t];
      if (pk & (1 << 24)) {  // wave-uniform: whole wave shares (n,t)
        float4 tb = s_tbA[j * T + t];
        float4 xy = s_tbB[j * T + t];
        // Coalesced gather: 64 lanes -> 64 consecutive bf16 (one 128B line).
        float p = __bfloat162float(
            *(const __hip_bfloat16*)(pcol + (pk & 0xFFFFFF)));

        float s = fabsf(pb.x - tb.x) + fabsf(pb.y - tb.y) +
                  fabsf(pb.z - tb.z) + fabsf(pb.w - tb.w);
        float iw = fmaxf(fminf(px2, xy.z) - fmaxf(px1, xy.x), 0.f);
        float ih = fmaxf(fminf(py2, xy.w) - fmaxf(py1, xy.y), 0.f);
        float inter = iw * ih;
        float uni = fmaf(tb.z, tb.w, area_p) - inter;
        float r = __builtin_amdgcn_rcpf(uni);  // <=1 ulp; budget 8.9e-3
        acc[j] = fmaf(0.25f, s, acc[j]) - p - inter * r;
      }
    }
  }

  // Cross-wave reduction through LDS (stride 9: conflict-free writes).
#pragma unroll
  for (int j = 0; j < NB; ++j) s_red[(wave * 64 + lane) * RS + j] = acc[j];
  __syncthreads();

  // 512 threads -> 512 (q,n) outputs.
  {
    int ql = tid >> 3;  // 0..63
    int j = tid & 7;    // 0..7
    float s = 0.f;
#pragma unroll
    for (int w = 0; w < 8; ++w) s += s_red[(w * 64 + ql) * RS + j];
    out[(size_t)(q0 + ql) * N + n0 + j] = s * s_rden[j];
  }
}

extern "C" void kernel_launch(void* const* d_in, const int* in_sizes, int n_in,
                              void* d_out, int out_size, void* d_ws, size_t ws_size,
                              hipStream_t stream) {
  const float* logits = (const float*)d_in[0];
  const float* pboxes = (const float*)d_in[1];
  const int* labels = (const int*)d_in[2];
  const float* tboxes = (const float*)d_in[3];
  const int* valid = (const int*)d_in[4];
  const int* ovalid = (const int*)d_in[5];
  float* out = (float*)d_out;

  // Workspace: transposed bf16 probs P2[T][C][Q] = 36*42*2048*2 B = 6.2 MB.
  __hip_bfloat16* P2 = (__hip_bfloat16*)d_ws;

  dim3 g1(Q / 64, T);
  softmax_transpose_kernel<<<g1, 256, 0, stream>>>(logits, P2);

  dim3 g2(Q / 64, N / NB);
  cost_kernel<<<g2, 512, 0, stream>>>(P2, pboxes, labels, tboxes, valid, ovalid, out);
}